// Round 3
// baseline (84.461 us; speedup 1.0000x reference)
//
#include <hip/hip_runtime.h>
#include <math.h>

#define N_LAYERS 5
#define NG 20

// ---------------------------------------------------------------------------
// Fused single kernel, no workspace.
//
// Phase 1 (per block): threads 0..19 build the 20 shared U3 gate matrices
//   into LDS from 240 B of weights (L3/L2-resident broadcast).
// Phase 2 (per block): compose the 16x16 layer unitary W via the shuffle
//   scheme verified in round 2 — thread t = col*16 + row propagates one
//   amplitude; butterflies via __shfl_xor across row bits (masks <= 8 stay
//   inside the 64-lane wave); ring CNOTs are shuffled selects. Layer loop
//   ROLLED: per-dispatch I$ invalidation + the harness's 268 MB poison-fill
//   thrash L2/L3 every iteration, so small code is king (v1 lesson: 21 KB
//   straight-line code = 63.5 us of serial cold-I$ streaming).
// Phase 3: per-sample encoding + psi = W * psi0 with W read from LDS
//   (uniform address -> broadcast, float4 -> ds_read_b128, conflict-free),
//   j-loop rolled with the +/- butterfly folded in (no p[] array, all
//   register arrays statically indexed).
//
// Removes: compose kernel launch, compose->qmain serialization, and the
// d_ws read (our only dependency on the re-poisoned workspace).
// ---------------------------------------------------------------------------
__global__ __launch_bounds__(256) void qfused(const float* __restrict__ x,
                                              const float* __restrict__ w,
                                              float* __restrict__ out) {
    __shared__ float g[NG][8];
    __shared__ __align__(16) float Wl[512];   // W[(row*16+col)*2 + {0,1}]
    const int t = threadIdx.x;

    if (t < NG) {
        float th = w[t * 3 + 0], ph = w[t * 3 + 1], la = w[t * 3 + 2];
        float st, ct, sl, cl, sp, cp, spl, cpl;
        sincosf(th * 0.5f, &st, &ct);
        sincosf(la, &sl, &cl);
        sincosf(ph, &sp, &cp);
        sincosf(ph + la, &spl, &cpl);
        g[t][0] = ct;        g[t][1] = 0.0f;
        g[t][2] = -cl * st;  g[t][3] = -sl * st;
        g[t][4] = cp * st;   g[t][5] = sp * st;
        g[t][6] = cpl * ct;  g[t][7] = spl * ct;
    }
    __syncthreads();

    {   // ---- compose W (one amplitude per thread) ----
        const int row = t & 15;   // output basis index (wire0 = bit3)
        const int col = t >> 4;   // input basis column
        float wr = (row == col) ? 1.0f : 0.0f;
        float wi = 0.0f;

#pragma unroll 1
        for (int l = 0; l < N_LAYERS; ++l) {
#pragma unroll
            for (int q = 0; q < 4; ++q) {
                const float* gm = g[l * 4 + q];
                const float m00r = gm[0];
                const float m01r = gm[2], m01i = gm[3];
                const float m10r = gm[4], m10i = gm[5];
                const float m11r = gm[6], m11i = gm[7];
                const int stride = 8 >> q;

                const float pr = __shfl_xor(wr, stride, 64);
                const float pi = __shfl_xor(wi, stride, 64);
                const bool up = (row & stride) != 0;

                const float cAr = up ? m11r : m00r;
                const float cAi = up ? m11i : 0.0f;
                const float cBr = up ? m10r : m01r;
                const float cBi = up ? m10i : m01i;

                const float nr = cAr * wr - cAi * wi + cBr * pr - cBi * pi;
                const float ni = cAr * wi + cAi * wr + cBr * pi + cBi * pr;
                wr = nr; wi = ni;
            }
            // ring CNOTs (0,1)(1,2)(2,3)(3,0): row permutation
#pragma unroll
            for (int e = 0; e < 4; ++e) {
                const int cm = 8 >> e;
                const int tm = 8 >> ((e + 1) & 3);
                const float pr = __shfl_xor(wr, tm, 64);
                const float pi = __shfl_xor(wi, tm, 64);
                if (row & cm) { wr = pr; wi = pi; }
            }
        }
        Wl[(row * 16 + col) * 2 + 0] = wr;
        Wl[(row * 16 + col) * 2 + 1] = wi;
    }
    __syncthreads();

    // ---- per-sample path ----
    const int b = blockIdx.x * 256 + t;
    const float4 xv = ((const float4*)x)[b];
    const float xs[4] = {xv.x, xv.y, xv.z, xv.w};

    // encoding columns: [cos(x/2), e^{ix} sin(x/2)]
    float vr[4][2], vi[4][2];
#pragma unroll
    for (int i = 0; i < 4; i++) {
        const float st = __sinf(xs[i] * 0.5f);
        const float ct = __cosf(xs[i] * 0.5f);
        const float sx = __sinf(xs[i]);
        const float cx = __cosf(xs[i]);
        vr[i][0] = ct;      vi[i][0] = 0.0f;
        vr[i][1] = cx * st; vi[i][1] = sx * st;
    }

    // tensor product -> 16 complex amps (wire0 = bit3)
    float w01r[4], w01i[4], w23r[4], w23i[4];
#pragma unroll
    for (int a = 0; a < 2; a++) {
#pragma unroll
        for (int c = 0; c < 2; c++) {
            w01r[a * 2 + c] = vr[0][a] * vr[1][c] - vi[0][a] * vi[1][c];
            w01i[a * 2 + c] = vr[0][a] * vi[1][c] + vi[0][a] * vr[1][c];
            w23r[a * 2 + c] = vr[2][a] * vr[3][c] - vi[2][a] * vi[3][c];
            w23i[a * 2 + c] = vr[2][a] * vi[3][c] + vi[2][a] * vr[3][c];
        }
    }
    float sr[16], si[16];
#pragma unroll
    for (int hi = 0; hi < 4; hi++) {
#pragma unroll
        for (int lo = 0; lo < 4; lo++) {
            sr[hi * 4 + lo] = w01r[hi] * w23r[lo] - w01i[hi] * w23i[lo];
            si[hi * 4 + lo] = w01r[hi] * w23i[lo] + w01i[hi] * w23r[lo];
        }
    }

    // psi_j = sum_k W[j][k] * s_k ; butterfly signs folded into the j loop.
    // W from LDS: uniform address across lanes -> broadcast, float4 ->
    // ds_read_b128. FMA order per k matches the verified kernel exactly.
    float z0 = 0.0f, z1 = 0.0f, z2 = 0.0f, z3 = 0.0f;
    const float4* Wv = (const float4*)Wl;   // row j = Wv[j*8 .. j*8+7]
#pragma unroll 1
    for (int j = 0; j < 16; ++j) {
        float prr = 0.0f, pii = 0.0f;
#pragma unroll
        for (int kq = 0; kq < 8; ++kq) {
            const float4 wv = Wv[j * 8 + kq];
            const int k0 = kq * 2;
            prr = fmaf(wv.x, sr[k0], prr);
            prr = fmaf(-wv.y, si[k0], prr);
            pii = fmaf(wv.x, si[k0], pii);
            pii = fmaf(wv.y, sr[k0], pii);
            prr = fmaf(wv.z, sr[k0 + 1], prr);
            prr = fmaf(-wv.w, si[k0 + 1], prr);
            pii = fmaf(wv.z, si[k0 + 1], pii);
            pii = fmaf(wv.w, sr[k0 + 1], pii);
        }
        const float pj = prr * prr + pii * pii;
        const float s3 = (j & 1) ? -1.0f : 1.0f;
        const float s2 = (j & 2) ? -1.0f : 1.0f;
        const float s1 = (j & 4) ? -1.0f : 1.0f;
        const float s0 = (j & 8) ? -1.0f : 1.0f;
        z3 = fmaf(s3, pj, z3);
        z2 = fmaf(s2, pj, z2);
        z1 = fmaf(s1, pj, z1);
        z0 = fmaf(s0, pj, z0);
    }

    ((float4*)out)[b] = make_float4(z0, z1, z2, z3);
}

extern "C" void kernel_launch(void* const* d_in, const int* in_sizes, int n_in,
                              void* d_out, int out_size, void* d_ws, size_t ws_size,
                              hipStream_t stream) {
    const float* x = (const float*)d_in[0];   // [B,4] fp32
    const float* w = (const float*)d_in[1];   // [5,4,3] fp32
    float* out = (float*)d_out;               // [B,4] fp32
    const int b = in_sizes[0] / 4;

    qfused<<<b / 256, 256, 0, stream>>>(x, w, out);
}